// Round 10
// baseline (305.196 us; speedup 1.0000x reference)
//
#include <hip/hip_runtime.h>
#include <math.h>

#define BB 32
#define DD 2048
#define NKVH 4
#define HDIM 128
#define MAXS 4096
#define FFD 8192
#define POS 4095
#define EPSV 1e-5f
#define SCALE 0.08838834764831845f
#define ASPLIT 32
#define SPOS 128   // positions per split

// workspace offsets (floats)
#define OFF_QT   0u        // 32 x 2048 q (NORMAL layout, atomic target)
#define OFF_KT   65536u    // 512 x 32 (transposed)
#define OFF_VT   81920u    // 512 x 32
#define OFF_G1   98304u    // 8192 x 32
#define OFF_G2   360448u   // 8192 x 32
#define ZERO_N   622592u   // contiguous atomic-target region [0, ZERO_N)
#define OFF_XAT  622592u   // 2048 x 32
#define OFF_PML  720896u   // 32*32*16 x {m,l} = 32768
#define OFF_PACC 753664u   // 32*32*16 x 128 = 2097152
#define OFF_YT   2850816u  // 2048 x 32
#define OFF_H    2916352u  // 32 x 2048 (normal)
#define OFF_XFT  2981888u  // 2048 x 32
#define OFF_KFIX 3047424u  // 32 x 16 x 512 (last-16-pos K records, 4095 patched)
#define OFF_VFIX 3309568u  // 32 x 16 x 512

#define VM_WAIT8  asm volatile("s_waitcnt vmcnt(8)" ::: "memory")
#define VM_WAIT0  asm volatile("s_waitcnt vmcnt(0)" ::: "memory")
#define LG_WAIT0  asm volatile("s_waitcnt lgkmcnt(0)" ::: "memory")
#define SCHED0    __builtin_amdgcn_sched_barrier(0)
#define SBAR      __builtin_amdgcn_s_barrier()

#define REP32(M) M(0) M(1) M(2) M(3) M(4) M(5) M(6) M(7) M(8) M(9) M(10) M(11) M(12) M(13) M(14) M(15) M(16) M(17) M(18) M(19) M(20) M(21) M(22) M(23) M(24) M(25) M(26) M(27) M(28) M(29) M(30) M(31)
#define REP32A(M,X) M(0,X) M(1,X) M(2,X) M(3,X) M(4,X) M(5,X) M(6,X) M(7,X) M(8,X) M(9,X) M(10,X) M(11,X) M(12,X) M(13,X) M(14,X) M(15,X) M(16,X) M(17,X) M(18,X) M(19,X) M(20,X) M(21,X) M(22,X) M(23,X) M(24,X) M(25,X) M(26,X) M(27,X) M(28,X) M(29,X) M(30,X) M(31,X)

#define DECLA(i) float a##i = 0.f;
#define FMA1(i,k) a##i = fmaf(ap[(k)*32 + (i)], w##k, a##i);
#define STORET(i) tl[i] = a##i;
#define ATOMN(i) atomicAdd(C + (size_t)(i)*N + n, a##i);

// 32-batch GEMV: C[b][n] += sum_d At[d][b] * W[d][n].  (r2-proven body, no nt)
template<int N, int CH, bool TOUT>
__device__ __forceinline__ void gemv_body(const float* __restrict__ At,
                                          const float* __restrict__ W,
                                          float* __restrict__ C, int colblk,
                                          float* tile) {
    int tid = (int)threadIdx.x;
    int n = colblk * 256 + tid;
    int d0 = blockIdx.y * CH;
    const float* Wp = W + (size_t)d0 * N + n;
    const float* ap = At + (size_t)d0 * 32;
    REP32(DECLA)
#pragma unroll 4
    for (int dd = 0; dd < CH; dd += 4) {
        float w0 = Wp[0];
        float w1 = Wp[(size_t)N];
        float w2 = Wp[(size_t)N * 2];
        float w3 = Wp[(size_t)N * 3];
        REP32A(FMA1, 0)
        REP32A(FMA1, 1)
        REP32A(FMA1, 2)
        REP32A(FMA1, 3)
        Wp += (size_t)N * 4;
        ap += 128;
    }
    if constexpr (TOUT) {
        float* tl = tile + tid * 33;
        REP32(STORET)
        __syncthreads();
        float* cb = C + (size_t)colblk * 256 * 32;
#pragma unroll
        for (int i = 0; i < 32; ++i) {
            int f = i * 256 + tid;
            atomicAdd(cb + f, tile[(f >> 5) * 33 + (f & 31)]);
        }
    } else {
        REP32(ATOMN)
    }
}

template<int N, int CH, bool TOUT>
__global__ __launch_bounds__(256) void gemv32_kernel(const float* __restrict__ At,
                                                     const float* __restrict__ W,
                                                     float* __restrict__ C) {
    if constexpr (TOUT) {
        __shared__ float tile[256 * 33];
        gemv_body<N, CH, true>(At, W, C, blockIdx.x, tile);
    } else {
        gemv_body<N, CH, false>(At, W, C, blockIdx.x, nullptr);
    }
}

template<int N, int CH, int HALF>
__global__ __launch_bounds__(256) void gemv32_dual_kernel(const float* __restrict__ At,
        const float* __restrict__ W0, const float* __restrict__ W1,
        float* __restrict__ C0, float* __restrict__ C1) {
    __shared__ float tile[256 * 33];
    int bx = blockIdx.x;
    if (bx < HALF) gemv_body<N, CH, true>(At, W0, C0, bx, tile);
    else           gemv_body<N, CH, true>(At, W1, C1, bx - HALF, tile);
}

// fused: blocks 0..607 zero the atomic-target region (float4); blocks 608..639
// do rmsnorm row (b = bx-608): outT[d][b] = norm, cpy = raw input copy.
__global__ void zero_rms_kernel(float* __restrict__ p, const float* __restrict__ in,
                                const float* __restrict__ g, float* __restrict__ outT,
                                float* __restrict__ cpy) {
    int bx = blockIdx.x, tid = threadIdx.x;
    if (bx < 608) {
        ((float4*)p)[bx * 256 + tid] = (float4){0.f, 0.f, 0.f, 0.f};
        return;
    }
    int b = bx - 608;
    const float* row = in + b * DD;
    float v[8];
    float ss = 0.f;
#pragma unroll
    for (int i = 0; i < 8; ++i) { v[i] = row[tid + i * 256]; ss += v[i] * v[i]; }
#pragma unroll
    for (int off = 32; off; off >>= 1) ss += __shfl_xor(ss, off);
    __shared__ float red[4];
    if ((tid & 63) == 0) red[tid >> 6] = ss;
    __syncthreads();
    ss = red[0] + red[1] + red[2] + red[3];
    float scale = rsqrtf(ss * (1.f / DD) + EPSV);
#pragma unroll
    for (int i = 0; i < 8; ++i) {
        int idx = tid + i * 256;
        outT[(size_t)idx * 32 + b] = v[i] * g[idx] * scale;
        cpy[b * DD + idx] = v[i];
    }
}

// plain rmsnorm (used for the FFN norm)
__global__ void rmsnorm_kernel(const float* __restrict__ in, const float* __restrict__ g,
                               float* __restrict__ outT, float* __restrict__ cpy) {
    int b = blockIdx.x;
    int tid = threadIdx.x;
    const float* row = in + b * DD;
    float v[8];
    float ss = 0.f;
#pragma unroll
    for (int i = 0; i < 8; ++i) { v[i] = row[tid + i * 256]; ss += v[i] * v[i]; }
#pragma unroll
    for (int off = 32; off; off >>= 1) ss += __shfl_xor(ss, off);
    __shared__ float red[4];
    if ((tid & 63) == 0) red[tid >> 6] = ss;
    __syncthreads();
    ss = red[0] + red[1] + red[2] + red[3];
    float scale = rsqrtf(ss * (1.f / DD) + EPSV);
#pragma unroll
    for (int i = 0; i < 8; ++i) {
        int idx = tid + i * 256;
        outT[(size_t)idx * 32 + b] = v[i] * g[idx] * scale;
        if (cpy) cpy[b * DD + idx] = v[i];
    }
}

// materialize last-16-position K/V records [b][16][512] (float2 grain);
// pos 4095 roped on the fly from kT/vT (cache inputs never mutated).
__global__ void fixrope_kernel(const float* __restrict__ kc, const float* __restrict__ vc,
                               const float* __restrict__ kT, const float* __restrict__ vT,
                               const float* __restrict__ cosb, const float* __restrict__ sinb,
                               float* __restrict__ kfix, float* __restrict__ vfix) {
    int idx = blockIdx.x * 256 + threadIdx.x;  // 32*16*256 pairs = 131072
    int b = idx >> 12, rem = idx & 4095;
    int pos = rem >> 8, pr = rem & 255;        // pr = kvh*64 + hd2
    int gpos = 4080 + pos;
    float2 kv, vv;
    if (gpos == POS) {
        int hd2 = pr & 63;
        float c = cosb[hd2], s = sinb[hd2];
        int col = pr * 2;
        float k0 = kT[(size_t)col * 32 + b], k1 = kT[(size_t)(col + 1) * 32 + b];
        float v0 = vT[(size_t)col * 32 + b], v1 = vT[(size_t)(col + 1) * 32 + b];
        kv = (float2){k0 * c - k1 * s, k0 * s + k1 * c};
        vv = (float2){v0 * c - v1 * s, v0 * s + v1 * c};
    } else {
        size_t o = ((size_t)(b * MAXS + gpos)) * 256 + pr;
        kv = ((const float2*)kc)[o]; vv = ((const float2*)vc)[o];
    }
    size_t d = (size_t)b * 4096 + pos * 256 + pr;
    ((float2*)kfix)[d] = kv; ((float2*)vfix)[d] = vv;
}

// attention (r4-proven, measured 154-157 us): grid 1024 = (b, 32 splits of 128
// pos), all 4 kvh per block. K/V staged via global_load_lds, double-buffered,
// counted vmcnt(8), raw barriers. 16 sub-tiles of 16 pos (8 K + 8 V).
__global__ __launch_bounds__(256, 2) void attn_stage_kernel(
    const float* __restrict__ qn, const float* __restrict__ kc, const float* __restrict__ vc,
    const float* __restrict__ kfix, const float* __restrict__ vfix,
    float* __restrict__ pml, float* __restrict__ pacc) {
    int split = blockIdx.x & 31, b = blockIdx.x >> 5;
    int tid = threadIdx.x, lane = tid & 63, wv = tid >> 6;
    __shared__ float kbuf[2][8192];   // 2 x 32 KB (16 pos x 4 kvh x 128)
    __shared__ float p_s[128][16];    // [pos][head] scores -> exp
    int qpos = tid >> 4, qhead = tid & 15;
    int qr = qpos * 4 + (qhead >> 2);          // LDS 512B-row id (0..63)
    int vh = tid >> 4, c16 = tid & 15, vkvh = vh >> 2;
    int t0 = split * SPOS;

    // q pre-rotated: qrot[j] = q[b][qhead*128 + ((j+qr)&31)*4 ..]
    float4 qrot[32];
#pragma unroll
    for (int j = 0; j < 32; ++j) {
        int g = (j + qr) & 31;
        qrot[j] = *(const float4*)(qn + (size_t)b * DD + qhead * HDIM + g * 4);
    }
    float4 av0 = {0, 0, 0, 0}, av1 = {0, 0, 0, 0};

    auto stage = [&](int t) {
        int s = t & 7;
        const float* base;
        if (t < 8) base = (split == 31 && s == 7) ? kfix + (size_t)b * 8192
                                                  : kc + ((size_t)b * MAXS + t0 + s * 16) * 512;
        else       base = (split == 31 && s == 7) ? vfix + (size_t)b * 8192
                                                  : vc + ((size_t)b * MAXS + t0 + s * 16) * 512;
        const float* g = base + wv * 2048 + lane * 4;   // per-lane global src
        float* l = &kbuf[t & 1][wv * 2048];             // wave-uniform LDS base
#pragma unroll
        for (int i = 0; i < 8; ++i)
            __builtin_amdgcn_global_load_lds(
                (const __attribute__((address_space(1))) void*)(g + i * 256),
                (__attribute__((address_space(3))) void*)(l + i * 256), 16, 0, 0);
    };

    stage(0);
    for (int t = 0; t < 16; ++t) {
        if (t < 15) { stage(t + 1); VM_WAIT8; } else { VM_WAIT0; }
        SCHED0; SBAR;
        if (t == 8) {
            // softmax: wave w handles heads 4w..4w+3 (same heads it uses in PV)
#pragma unroll
            for (int hh = 0; hh < 4; ++hh) {
                int h = wv * 4 + hh;
                float e0 = p_s[lane][h], e1 = p_s[lane + 64][h];
                float m = fmaxf(e0, e1);
#pragma unroll
                for (int off = 32; off; off >>= 1) m = fmaxf(m, __shfl_xor(m, off));
                e0 = __expf(e0 - m); e1 = __expf(e1 - m);
                p_s[lane][h] = e0; p_s[lane + 64][h] = e1;
                float l2 = e0 + e1;
#pragma unroll
                for (int off = 32; off; off >>= 1) l2 += __shfl_xor(l2, off);
                if (lane == 0) {
                    int idx = ((b * ASPLIT + split) * 16 + h) * 2;
                    pml[idx] = m; pml[idx + 1] = l2;
                }
            }
        }
        const float* kb = kbuf[t & 1];
        if (t < 8) {
            float4 acc = {0, 0, 0, 0};
            const float* rowp = kb + qr * 128;
#pragma unroll
            for (int j = 0; j < 32; ++j) {
                int g = (j + qr) & 31;
                float4 k4 = *(const float4*)(rowp + g * 4);
                acc.x = fmaf(k4.x, qrot[j].x, acc.x);
                acc.y = fmaf(k4.y, qrot[j].y, acc.y);
                acc.z = fmaf(k4.z, qrot[j].z, acc.z);
                acc.w = fmaf(k4.w, qrot[j].w, acc.w);
            }
            p_s[t * 16 + qpos][qhead] = (acc.x + acc.y + acc.z + acc.w) * SCALE;
        } else {
            int s = t - 8;
            const float* vrow = kb + vkvh * 128 + c16 * 4;
#pragma unroll
            for (int p = 0; p < 16; ++p) {
                float pw = p_s[s * 16 + p][vh];
                float4 v0 = *(const float4*)(vrow + p * 512);
                float4 v1 = *(const float4*)(vrow + p * 512 + 64);
                av0.x = fmaf(pw, v0.x, av0.x); av0.y = fmaf(pw, v0.y, av0.y);
                av0.z = fmaf(pw, v0.z, av0.z); av0.w = fmaf(pw, v0.w, av0.w);
                av1.x = fmaf(pw, v1.x, av1.x); av1.y = fmaf(pw, v1.y, av1.y);
                av1.z = fmaf(pw, v1.z, av1.z); av1.w = fmaf(pw, v1.w, av1.w);
            }
        }
        LG_WAIT0; SCHED0; SBAR;
    }
    size_t pbase = ((size_t)(b * ASPLIT + split) * 16 + vh) * HDIM;
    *(float4*)(pacc + pbase + c16 * 4) = av0;
    *(float4*)(pacc + pbase + 64 + c16 * 4) = av1;
}

// combine split partials: grid 512 = (b, h), 128 threads; writes yT
__global__ void attn_combine_kernel(const float* __restrict__ pml,
                                    const float* __restrict__ pacc, float* __restrict__ yT) {
    int bid = blockIdx.x;
    int b = bid >> 4, h = bid & 15;
    int d = threadIdx.x;
    float M = -INFINITY;
#pragma unroll 8
    for (int s = 0; s < ASPLIT; ++s)
        M = fmaxf(M, pml[((b * ASPLIT + s) * 16 + h) * 2]);
    float denom = 0.f, acc = 0.f;
#pragma unroll 4
    for (int s = 0; s < ASPLIT; ++s) {
        int idx = (b * ASPLIT + s) * 16 + h;
        float e = __expf(pml[idx * 2] - M);
        denom += pml[idx * 2 + 1] * e;
        acc += e * pacc[(size_t)idx * HDIM + d];
    }
    yT[(size_t)(h * HDIM + d) * 32 + b] = acc / denom;
}

__global__ void silu_mul_kernel(float* __restrict__ g1, const float* __restrict__ g2) {
    int i = blockIdx.x * 256 + threadIdx.x; // 65536 float4s
    float4 a = ((const float4*)g1)[i];
    float4 b4 = ((const float4*)g2)[i];
    a.x = a.x * b4.x / (1.f + __expf(-a.x));
    a.y = a.y * b4.y / (1.f + __expf(-a.y));
    a.z = a.z * b4.z / (1.f + __expf(-a.z));
    a.w = a.w * b4.w / (1.f + __expf(-a.w));
    ((float4*)g1)[i] = a;
}

extern "C" void kernel_launch(void* const* d_in, const int* in_sizes, int n_in,
                              void* d_out, int out_size, void* d_ws, size_t ws_size,
                              hipStream_t stream) {
    (void)in_sizes; (void)n_in; (void)out_size; (void)ws_size;
    const float* x    = (const float*)d_in[0];
    const float* cosb = (const float*)d_in[1];
    const float* sinb = (const float*)d_in[2];
    const float* kc   = (const float*)d_in[3];
    const float* vc   = (const float*)d_in[4];
    const float* wra  = (const float*)d_in[5];
    const float* wq   = (const float*)d_in[6];
    const float* wk   = (const float*)d_in[7];
    const float* wv   = (const float*)d_in[8];
    const float* wo   = (const float*)d_in[9];
    const float* wrf  = (const float*)d_in[10];
    const float* w1   = (const float*)d_in[11];
    const float* w2   = (const float*)d_in[12];
    const float* w3   = (const float*)d_in[13];
    float* out = (float*)d_out;
    float* ws  = (float*)d_ws;

    float* qn   = ws + OFF_QT;
    float* kT   = ws + OFF_KT;
    float* vT   = ws + OFF_VT;
    float* g1T  = ws + OFF_G1;
    float* g2T  = ws + OFF_G2;
    float* xaT  = ws + OFF_XAT;
    float* pml  = ws + OFF_PML;
    float* pacc = ws + OFF_PACC;
    float* yT   = ws + OFF_YT;
    float* h    = ws + OFF_H;
    float* xfT  = ws + OFF_XFT;
    float* kfix = ws + OFF_KFIX;
    float* vfix = ws + OFF_VFIX;

    // fused: zero atomic-target region + rmsnorm1 (xaT = rmsnorm(x)^T, h = x)
    zero_rms_kernel<<<640, 256, 0, stream>>>(ws, x, wra, xaT, h);
    // q (NORMAL layout), k/v (transposed for rope) — 32 split-K rounds
    gemv32_kernel<2048, 64, false><<<dim3(8, 32), 256, 0, stream>>>(xaT, wq, qn);
    gemv32_dual_kernel<512, 32, 2><<<dim3(4, 64), 256, 0, stream>>>(xaT, wk, wv, kT, vT);
    // patched last-16 records with rope applied to pos 4095 (cache NOT mutated)
    fixrope_kernel<<<512, 256, 0, stream>>>(kc, vc, kT, vT, cosb, sinb, kfix, vfix);
    // attention (r4 structure, measured floor)
    attn_stage_kernel<<<1024, 256, 0, stream>>>(qn, kc, vc, kfix, vfix, pml, pacc);
    attn_combine_kernel<<<512, 128, 0, stream>>>(pml, pacc, yT);
    // h = x + y @ wo — 32 split-K rounds
    gemv32_kernel<2048, 64, false><<<dim3(8, 32), 256, 0, stream>>>(yT, wo, h);
    // xfT = rmsnorm(h)^T, out = h
    rmsnorm_kernel<<<32, 256, 0, stream>>>(h, wrf, xfT, out);
    // g1 = xf@w1, g2 = xf@w2 — 8 split-K rounds
    gemv32_dual_kernel<8192, 256, 32><<<dim3(64, 8), 256, 0, stream>>>(xfT, w1, w2, g1T, g2T);
    // g1 = silu(g1)*g2 (float4)
    silu_mul_kernel<<<256, 256, 0, stream>>>(g1T, g2T);
    // out += g1 @ w3 — 64 split-K rounds (control: unchanged)
    gemv32_kernel<2048, 128, false><<<dim3(8, 64), 256, 0, stream>>>(g1T, w3, out);
}

// Round 11
// 292.156 us; speedup vs baseline: 1.0446x; 1.0446x over previous
//
#include <hip/hip_runtime.h>
#include <math.h>

#define BB 32
#define DD 2048
#define NKVH 4
#define HDIM 128
#define MAXS 4096
#define FFD 8192
#define POS 4095
#define EPSV 1e-5f
#define SCALE 0.08838834764831845f
#define ASPLIT 32
#define SPOS 128   // positions per split

// workspace offsets (floats)
#define OFF_QN   0u        // 32 x 2048 q (normal, atomic target)
#define OFF_KN   65536u    // 32 x 512 (normal)
#define OFF_VN   81920u    // 32 x 512
#define OFF_G1   98304u    // 8192 x 32 (transposed)
#define OFF_G2   360448u   // 8192 x 32
#define ZERO_N   622592u   // contiguous atomic-target region [0, ZERO_N)
#define OFF_XAT  622592u   // 2048 x 32
#define OFF_PML  720896u   // 32*32*16 x {m,l}
#define OFF_PACC 753664u   // 32*32*16 x 128
#define OFF_YT   2850816u  // 2048 x 32
#define OFF_H    2916352u  // 32 x 2048 (normal)
#define OFF_XFT  2981888u  // 2048 x 32

#define VM_WAIT8  asm volatile("s_waitcnt vmcnt(8)" ::: "memory")
#define VM_WAIT0  asm volatile("s_waitcnt vmcnt(0)" ::: "memory")
#define LG_WAIT0  asm volatile("s_waitcnt lgkmcnt(0)" ::: "memory")
#define SCHED0    __builtin_amdgcn_sched_barrier(0)
#define SBAR      __builtin_amdgcn_s_barrier()

#define REP32(M) M(0) M(1) M(2) M(3) M(4) M(5) M(6) M(7) M(8) M(9) M(10) M(11) M(12) M(13) M(14) M(15) M(16) M(17) M(18) M(19) M(20) M(21) M(22) M(23) M(24) M(25) M(26) M(27) M(28) M(29) M(30) M(31)
#define REP32A(M,X) M(0,X) M(1,X) M(2,X) M(3,X) M(4,X) M(5,X) M(6,X) M(7,X) M(8,X) M(9,X) M(10,X) M(11,X) M(12,X) M(13,X) M(14,X) M(15,X) M(16,X) M(17,X) M(18,X) M(19,X) M(20,X) M(21,X) M(22,X) M(23,X) M(24,X) M(25,X) M(26,X) M(27,X) M(28,X) M(29,X) M(30,X) M(31,X)

#define DECLA(i) float a##i = 0.f;
#define FMA1(i,k) a##i = fmaf(ap[(k)*32 + (i)], w##k, a##i);
#define STORET(i) tl[i] = a##i;
#define ATOMN(i) atomicAdd(C + (size_t)(i)*N + n, a##i);

// 32-batch GEMV: C[b][n] += sum_d At[d][b] * W[d][n].  (r3-proven body)
template<int N, int CH, bool TOUT>
__device__ __forceinline__ void gemv_body(const float* __restrict__ At,
                                          const float* __restrict__ W,
                                          float* __restrict__ C, int colblk,
                                          float* tile) {
    int tid = (int)threadIdx.x;
    int n = colblk * 256 + tid;
    int d0 = blockIdx.y * CH;
    const float* Wp = W + (size_t)d0 * N + n;
    const float* ap = At + (size_t)d0 * 32;
    REP32(DECLA)
#pragma unroll 4
    for (int dd = 0; dd < CH; dd += 4) {
        float w0 = Wp[0];
        float w1 = Wp[(size_t)N];
        float w2 = Wp[(size_t)N * 2];
        float w3 = Wp[(size_t)N * 3];
        REP32A(FMA1, 0)
        REP32A(FMA1, 1)
        REP32A(FMA1, 2)
        REP32A(FMA1, 3)
        Wp += (size_t)N * 4;
        ap += 128;
    }
    if constexpr (TOUT) {
        float* tl = tile + tid * 33;
        REP32(STORET)
        __syncthreads();
        float* cb = C + (size_t)colblk * 256 * 32;
#pragma unroll
        for (int i = 0; i < 32; ++i) {
            int f = i * 256 + tid;
            atomicAdd(cb + f, tile[(f >> 5) * 33 + (f & 31)]);
        }
    } else {
        REP32(ATOMN)
    }
}

template<int N, int CH, bool TOUT>
__global__ __launch_bounds__(256) void gemv32_kernel(const float* __restrict__ At,
                                                     const float* __restrict__ W,
                                                     float* __restrict__ C) {
    if constexpr (TOUT) {
        __shared__ float tile[256 * 33];
        gemv_body<N, CH, true>(At, W, C, blockIdx.x, tile);
    } else {
        gemv_body<N, CH, false>(At, W, C, blockIdx.x, nullptr);
    }
}

template<int N, int CH, int HALF>
__global__ __launch_bounds__(256) void gemv32_dual_kernel(const float* __restrict__ At,
        const float* __restrict__ W0, const float* __restrict__ W1,
        float* __restrict__ C0, float* __restrict__ C1) {
    __shared__ float tile[256 * 33];
    int bx = blockIdx.x;
    if (bx < HALF) gemv_body<8192, CH, true>(At, W0, C0, bx, tile);
    else           gemv_body<8192, CH, true>(At, W1, C1, bx - HALF, tile);
}

// fused q/k/v GEMV: grid (12, 64). blocks 0..7 -> wq (N=2048, out qn),
// 8..9 -> wk (N=512, out kn), 10..11 -> wv (N=512, out vn). All normal layout.
__global__ __launch_bounds__(256) void gemv_qkv_kernel(const float* __restrict__ At,
        const float* __restrict__ wq, const float* __restrict__ wk,
        const float* __restrict__ wv, float* __restrict__ qn,
        float* __restrict__ kn, float* __restrict__ vn) {
    int bx = blockIdx.x;
    if (bx < 8)       gemv_body<2048, 32, false>(At, wq, qn, bx, nullptr);
    else if (bx < 10) gemv_body<512, 32, false>(At, wk, kn, bx - 8, nullptr);
    else              gemv_body<512, 32, false>(At, wv, vn, bx - 10, nullptr);
}

// fused: blocks 0..607 zero the atomic-target region (float4); blocks 608..639
// do rmsnorm row (b = bx-608): outT[d][b] = norm, cpy = raw input copy.
__global__ void zero_rms_kernel(float* __restrict__ p, const float* __restrict__ in,
                                const float* __restrict__ g, float* __restrict__ outT,
                                float* __restrict__ cpy) {
    int bx = blockIdx.x, tid = threadIdx.x;
    if (bx < 608) {
        ((float4*)p)[bx * 256 + tid] = (float4){0.f, 0.f, 0.f, 0.f};
        return;
    }
    int b = bx - 608;
    const float* row = in + b * DD;
    float v[8];
    float ss = 0.f;
#pragma unroll
    for (int i = 0; i < 8; ++i) { v[i] = row[tid + i * 256]; ss += v[i] * v[i]; }
#pragma unroll
    for (int off = 32; off; off >>= 1) ss += __shfl_xor(ss, off);
    __shared__ float red[4];
    if ((tid & 63) == 0) red[tid >> 6] = ss;
    __syncthreads();
    ss = red[0] + red[1] + red[2] + red[3];
    float scale = rsqrtf(ss * (1.f / DD) + EPSV);
#pragma unroll
    for (int i = 0; i < 8; ++i) {
        int idx = tid + i * 256;
        outT[(size_t)idx * 32 + b] = v[i] * g[idx] * scale;
        cpy[b * DD + idx] = v[i];
    }
}

// plain rmsnorm (FFN norm)
__global__ void rmsnorm_kernel(const float* __restrict__ in, const float* __restrict__ g,
                               float* __restrict__ outT, float* __restrict__ cpy) {
    int b = blockIdx.x;
    int tid = threadIdx.x;
    const float* row = in + b * DD;
    float v[8];
    float ss = 0.f;
#pragma unroll
    for (int i = 0; i < 8; ++i) { v[i] = row[tid + i * 256]; ss += v[i] * v[i]; }
#pragma unroll
    for (int off = 32; off; off >>= 1) ss += __shfl_xor(ss, off);
    __shared__ float red[4];
    if ((tid & 63) == 0) red[tid >> 6] = ss;
    __syncthreads();
    ss = red[0] + red[1] + red[2] + red[3];
    float scale = rsqrtf(ss * (1.f / DD) + EPSV);
#pragma unroll
    for (int i = 0; i < 8; ++i) {
        int idx = tid + i * 256;
        outT[(size_t)idx * 32 + b] = v[i] * g[idx] * scale;
        if (cpy) cpy[b * DD + idx] = v[i];
    }
}

// attention (r4-proven structure, 154-157 us): grid 1024 = (b, 32 splits of
// 128 pos), all 4 kvh per block. K/V staged via global_load_lds, double-
// buffered, counted vmcnt(8), raw barriers. 16 sub-tiles of 16 pos (8K + 8V).
// NEW: the pos-4095 record (stale in cache; inputs never mutated) is roped
// in-kernel: in split-31 blocks, wave 3 skips DMA chunks 6-7 of boundary
// tiles and ds_writes the roped K/V record computed from kn/vn + cos/sin.
__global__ __launch_bounds__(256, 2) void attn_stage_kernel(
    const float* __restrict__ qn, const float* __restrict__ kc, const float* __restrict__ vc,
    const float* __restrict__ kn, const float* __restrict__ vn,
    const float* __restrict__ cosb, const float* __restrict__ sinb,
    float* __restrict__ pml, float* __restrict__ pacc) {
    int split = blockIdx.x & 31, b = blockIdx.x >> 5;
    int tid = threadIdx.x, lane = tid & 63, wv = tid >> 6;
    __shared__ float kbuf[2][8192];   // 2 x 32 KB (16 pos x 4 kvh x 128)
    __shared__ float p_s[128][16];    // [pos][head] scores -> exp
    int qpos = tid >> 4, qhead = tid & 15;
    int qr = qpos * 4 + (qhead >> 2);          // LDS 512B-row id (0..63)
    int vh = tid >> 4, c16 = tid & 15, vkvh = vh >> 2;
    int t0 = split * SPOS;

    // q pre-rotated: qrot[j] = q[b][qhead*128 + ((j+qr)&31)*4 ..]
    float4 qrot[32];
#pragma unroll
    for (int j = 0; j < 32; ++j) {
        int g = (j + qr) & 31;
        qrot[j] = *(const float4*)(qn + (size_t)b * DD + qhead * HDIM + g * 4);
    }
    float4 av0 = {0, 0, 0, 0}, av1 = {0, 0, 0, 0};

    auto stage = [&](int t) {
        int s = t & 7;
        const float* base = (t < 8) ? kc + ((size_t)b * MAXS + t0 + s * 16) * 512
                                    : vc + ((size_t)b * MAXS + t0 + s * 16) * 512;
        const float* g = base + wv * 2048 + lane * 4;   // per-lane global src
        float* l = &kbuf[t & 1][wv * 2048];             // wave-uniform LDS base
        int imax = (split == 31 && s == 7 && wv == 3) ? 6 : 8; // skip pos-4095 record
#pragma unroll
        for (int i = 0; i < 8; ++i)
            if (i < imax)
                __builtin_amdgcn_global_load_lds(
                    (const __attribute__((address_space(1))) void*)(g + i * 256),
                    (__attribute__((address_space(3))) void*)(l + i * 256), 16, 0, 0);
    };

    stage(0);
    for (int t = 0; t < 16; ++t) {
        if (t < 15) {
            stage(t + 1);
            // rope-in-attn: fill the pos-4095 record of the boundary tile
            if (split == 31 && wv == 3 && (t == 6 || t == 14)) {
                const float* src = (t == 6) ? kn : vn;
                float* dst = &kbuf[(t + 1) & 1][7680 + lane * 8];
                int col0 = lane * 8;
#pragma unroll
                for (int m = 0; m < 4; ++m) {
                    int col = col0 + 2 * m;
                    int ci = (col & 127) >> 1;
                    float cc = cosb[ci], ssn = sinb[ci];
                    float x0 = src[b * 512 + col], x1 = src[b * 512 + col + 1];
                    dst[2 * m]     = x0 * cc - x1 * ssn;
                    dst[2 * m + 1] = x0 * ssn + x1 * cc;
                }
            }
            VM_WAIT8;
        } else { VM_WAIT0; }
        SCHED0; SBAR;
        if (t == 8) {
            // softmax: wave w handles heads 4w..4w+3 (same heads it uses in PV)
#pragma unroll
            for (int hh = 0; hh < 4; ++hh) {
                int h = wv * 4 + hh;
                float e0 = p_s[lane][h], e1 = p_s[lane + 64][h];
                float m = fmaxf(e0, e1);
#pragma unroll
                for (int off = 32; off; off >>= 1) m = fmaxf(m, __shfl_xor(m, off));
                e0 = __expf(e0 - m); e1 = __expf(e1 - m);
                p_s[lane][h] = e0; p_s[lane + 64][h] = e1;
                float l2 = e0 + e1;
#pragma unroll
                for (int off = 32; off; off >>= 1) l2 += __shfl_xor(l2, off);
                if (lane == 0) {
                    int idx = ((b * ASPLIT + split) * 16 + h) * 2;
                    pml[idx] = m; pml[idx + 1] = l2;
                }
            }
        }
        const float* kb = kbuf[t & 1];
        if (t < 8) {
            float4 acc = {0, 0, 0, 0};
            const float* rowp = kb + qr * 128;
#pragma unroll
            for (int j = 0; j < 32; ++j) {
                int g = (j + qr) & 31;
                float4 k4 = *(const float4*)(rowp + g * 4);
                acc.x = fmaf(k4.x, qrot[j].x, acc.x);
                acc.y = fmaf(k4.y, qrot[j].y, acc.y);
                acc.z = fmaf(k4.z, qrot[j].z, acc.z);
                acc.w = fmaf(k4.w, qrot[j].w, acc.w);
            }
            p_s[t * 16 + qpos][qhead] = (acc.x + acc.y + acc.z + acc.w) * SCALE;
        } else {
            int s = t - 8;
            const float* vrow = kb + vkvh * 128 + c16 * 4;
#pragma unroll
            for (int p = 0; p < 16; ++p) {
                float pw = p_s[s * 16 + p][vh];
                float4 v0 = *(const float4*)(vrow + p * 512);
                float4 v1 = *(const float4*)(vrow + p * 512 + 64);
                av0.x = fmaf(pw, v0.x, av0.x); av0.y = fmaf(pw, v0.y, av0.y);
                av0.z = fmaf(pw, v0.z, av0.z); av0.w = fmaf(pw, v0.w, av0.w);
                av1.x = fmaf(pw, v1.x, av1.x); av1.y = fmaf(pw, v1.y, av1.y);
                av1.z = fmaf(pw, v1.z, av1.z); av1.w = fmaf(pw, v1.w, av1.w);
            }
        }
        LG_WAIT0; SCHED0; SBAR;
    }
    size_t pbase = ((size_t)(b * ASPLIT + split) * 16 + vh) * HDIM;
    *(float4*)(pacc + pbase + c16 * 4) = av0;
    *(float4*)(pacc + pbase + 64 + c16 * 4) = av1;
}

// combine split partials: grid 512 = (b, h), 128 threads; writes yT
__global__ void attn_combine_kernel(const float* __restrict__ pml,
                                    const float* __restrict__ pacc, float* __restrict__ yT) {
    int bid = blockIdx.x;
    int b = bid >> 4, h = bid & 15;
    int d = threadIdx.x;
    float M = -INFINITY;
#pragma unroll 8
    for (int s = 0; s < ASPLIT; ++s)
        M = fmaxf(M, pml[((b * ASPLIT + s) * 16 + h) * 2]);
    float denom = 0.f, acc = 0.f;
#pragma unroll 4
    for (int s = 0; s < ASPLIT; ++s) {
        int idx = (b * ASPLIT + s) * 16 + h;
        float e = __expf(pml[idx * 2] - M);
        denom += pml[idx * 2 + 1] * e;
        acc += e * pacc[(size_t)idx * HDIM + d];
    }
    yT[(size_t)(h * HDIM + d) * 32 + b] = acc / denom;
}

__global__ void silu_mul_kernel(float* __restrict__ g1, const float* __restrict__ g2) {
    int i = blockIdx.x * 256 + threadIdx.x; // 65536 float4s
    float4 a = ((const float4*)g1)[i];
    float4 b4 = ((const float4*)g2)[i];
    a.x = a.x * b4.x / (1.f + __expf(-a.x));
    a.y = a.y * b4.y / (1.f + __expf(-a.y));
    a.z = a.z * b4.z / (1.f + __expf(-a.z));
    a.w = a.w * b4.w / (1.f + __expf(-a.w));
    ((float4*)g1)[i] = a;
}

extern "C" void kernel_launch(void* const* d_in, const int* in_sizes, int n_in,
                              void* d_out, int out_size, void* d_ws, size_t ws_size,
                              hipStream_t stream) {
    (void)in_sizes; (void)n_in; (void)out_size; (void)ws_size;
    const float* x    = (const float*)d_in[0];
    const float* cosb = (const float*)d_in[1];
    const float* sinb = (const float*)d_in[2];
    const float* kc   = (const float*)d_in[3];
    const float* vc   = (const float*)d_in[4];
    const float* wra  = (const float*)d_in[5];
    const float* wq   = (const float*)d_in[6];
    const float* wk   = (const float*)d_in[7];
    const float* wv   = (const float*)d_in[8];
    const float* wo   = (const float*)d_in[9];
    const float* wrf  = (const float*)d_in[10];
    const float* w1   = (const float*)d_in[11];
    const float* w2   = (const float*)d_in[12];
    const float* w3   = (const float*)d_in[13];
    float* out = (float*)d_out;
    float* ws  = (float*)d_ws;

    float* qn   = ws + OFF_QN;
    float* kn   = ws + OFF_KN;
    float* vn   = ws + OFF_VN;
    float* g1T  = ws + OFF_G1;
    float* g2T  = ws + OFF_G2;
    float* xaT  = ws + OFF_XAT;
    float* pml  = ws + OFF_PML;
    float* pacc = ws + OFF_PACC;
    float* yT   = ws + OFF_YT;
    float* h    = ws + OFF_H;
    float* xfT  = ws + OFF_XFT;

    // fused: zero atomic-target region + rmsnorm1 (xaT = rmsnorm(x)^T, h = x)
    zero_rms_kernel<<<640, 256, 0, stream>>>(ws, x, wra, xaT, h);
    // fused q/k/v GEMV (normal layouts) — r3-proven CH=32, 64 split rounds
    gemv_qkv_kernel<<<dim3(12, 64), 256, 0, stream>>>(xaT, wq, wk, wv, qn, kn, vn);
    // attention (rope for pos 4095 applied in-kernel; cache never mutated)
    attn_stage_kernel<<<1024, 256, 0, stream>>>(qn, kc, vc, kn, vn, cosb, sinb, pml, pacc);
    attn_combine_kernel<<<512, 128, 0, stream>>>(pml, pacc, yT);
    // h = x + y @ wo
    gemv32_kernel<2048, 32, false><<<dim3(8, 64), 256, 0, stream>>>(yT, wo, h);
    // xfT = rmsnorm(h)^T, out = h
    rmsnorm_kernel<<<32, 256, 0, stream>>>(h, wrf, xfT, out);
    // g1 = xf@w1, g2 = xf@w2 (transposed outputs) — r3-proven CH=128
    gemv32_dual_kernel<8192, 128, 32><<<dim3(64, 16), 256, 0, stream>>>(xfT, w1, w2, g1T, g2T);
    // g1 = silu(g1)*g2 (float4)
    silu_mul_kernel<<<256, 256, 0, stream>>>(g1T, g2T);
    // out += g1 @ w3
    gemv32_kernel<2048, 128, false><<<dim3(8, 64), 256, 0, stream>>>(g1T, w3, out);
}